// Round 9
// baseline (138.939 us; speedup 1.0000x reference)
//
#include <hip/hip_runtime.h>
#include <hip/hip_bf16.h>

typedef __attribute__((ext_vector_type(4))) float f32x4;
typedef __attribute__((ext_vector_type(8))) short s16x8;
typedef __attribute__((ext_vector_type(4))) short s16x4;

__device__ __forceinline__ unsigned short f2bf(float f) {
    unsigned int u; __builtin_memcpy(&u, &f, 4);
    u += 0x7fffu + ((u >> 16) & 1u);
    return (unsigned short)(u >> 16);
}
__device__ __forceinline__ float bf2f(unsigned short h) {
    unsigned int u = ((unsigned int)h) << 16;
    float f; __builtin_memcpy(&f, &u, 4);
    return f;
}
__device__ __forceinline__ s16x8 pack8(f32x4 a, f32x4 b) {
    s16x8 r;
    r[0] = (short)f2bf(a[0]); r[1] = (short)f2bf(a[1]);
    r[2] = (short)f2bf(a[2]); r[3] = (short)f2bf(a[3]);
    r[4] = (short)f2bf(b[0]); r[5] = (short)f2bf(b[1]);
    r[6] = (short)f2bf(b[2]); r[7] = (short)f2bf(b[3]);
    return r;
}

// ---------------------------------------------------------------------------
// build_M2 (grid 320):
//   blocks 0..127  : MS [128][256] bf16 + cbias[128] with agent proj fused
//   blocks 128..319: Wb [3][256][256] bf16 = {W_v, W_fc1, W_fc2} converted
// ---------------------------------------------------------------------------
__global__ __launch_bounds__(256) void build_M2(
    const float* __restrict__ W_qkv, const float* __restrict__ b_qkv,
    const float* __restrict__ agent, const float* __restrict__ W_agent,
    const float* __restrict__ b_agent,
    const float* __restrict__ W_fc1, const float* __restrict__ W_fc2,
    unsigned short* __restrict__ MS, float* __restrict__ cbias,
    unsigned short* __restrict__ Wb)
{
    const int i = blockIdx.x;
    const int t = threadIdx.x;
    if (i >= 128) {
        const int R0 = (i - 128) * 4;
        #pragma unroll
        for (int rr = 0; rr < 4; ++rr) {
            const int R = R0 + rr;
            const float* src = (R < 256) ? W_qkv + (size_t)(512 + R) * 256
                             : (R < 512) ? W_fc1 + (size_t)(R - 256) * 256
                                         : W_fc2 + (size_t)(R - 512) * 256;
            Wb[(size_t)R * 256 + t] = f2bf(src[t]);
        }
        return;
    }
    __shared__ float ag[256];
    __shared__ float qs[256];
    const int a = i & 63;
    const bool isS1 = (i < 64);
    ag[t] = agent[(size_t)a * 256 + t];
    __syncthreads();
    const int tp = isS1 ? t : 256 + t;
    {
        const float* wr = W_agent + (size_t)tp * 256;
        float q = 0.f;
        #pragma unroll 4
        for (int d = 0; d < 256; d += 4) {
            f32x4 wv = *(const f32x4*)(wr + d);
            q += ag[d] * wv[0] + ag[d + 1] * wv[1] + ag[d + 2] * wv[2] + ag[d + 3] * wv[3];
        }
        qs[t] = (q + b_agent[tp]) * 0.0625f;
    }
    __syncthreads();
    const float* W  = W_qkv + (isS1 ? 256 * 256 : 0);   // W_k : W_q
    const float* bb = b_qkv + (isS1 ? 256 : 0);
    float acc = 0.f, cb = 0.f;
    for (int dout = 0; dout < 256; ++dout) {
        const float q = qs[dout];
        acc += q * W[(size_t)dout * 256 + t];
        cb  += q * bb[dout];
    }
    MS[i * 256 + t] = f2bf(acc);
    if (t == 0) cbias[i] = cb;
}

// ---------------------------------------------------------------------------
// Streaming scores: per 64-token block:
//   S1T[n][a] f32 + stage-1 softmax partials;
//   P2[n][a] bf16 = FINALIZED stage-2 probs (swizzled rows), softmax done
//   via LDS transpose (reusing As) + 4-lane-group reduce.
// MFMA main loop identical to the proven R6 version.
// ---------------------------------------------------------------------------
__global__ __launch_bounds__(256) void xproj2(
    const float* __restrict__ x,
    const unsigned short* __restrict__ MS,
    const float* __restrict__ cbias,
    float* __restrict__ S1T,
    unsigned short* __restrict__ P2,
    float* __restrict__ mpart, float* __restrict__ lpart)
{
    __shared__ alignas(16) unsigned short As[64 * 256];   // 32KB; reused for S2 scores
    const int tid = threadIdx.x, lane = tid & 63, w = tid >> 6;
    const int lr = lane & 15, lq = lane >> 4;
    const long m0 = (long)blockIdx.x * 64;

    {
        const int k0 = (tid & 31) * 8;
        #pragma unroll
        for (int j = 0; j < 8; ++j) {
            const int row = (tid >> 5) + j * 8;
            const float* s = x + (m0 + row) * 256 + k0;
            f32x4 f0 = *(const f32x4*)s;
            f32x4 f1 = *(const f32x4*)(s + 4);
            *(s16x8*)((char*)As + row * 512 + ((k0 * 2) ^ ((row & 7) << 4))) = pack8(f0, f1);
        }
    }
    __syncthreads();

    f32x4 acc[4][2];
    const f32x4 zero = {0.f, 0.f, 0.f, 0.f};
    #pragma unroll
    for (int rf = 0; rf < 4; ++rf)
        #pragma unroll
        for (int j = 0; j < 2; ++j)
            acc[rf][j] = zero;

    #pragma unroll
    for (int ks = 0; ks < 8; ++ks) {
        const int kb = ks * 64 + lq * 16;
        s16x8 areg[4];
        #pragma unroll
        for (int rf = 0; rf < 4; ++rf) {
            const int row = rf * 16 + lr;
            areg[rf] = *(const s16x8*)((const char*)As + row * 512 + (kb ^ ((row & 7) << 4)));
        }
        s16x8 bfr[2];
        #pragma unroll
        for (int j = 0; j < 2; ++j) {
            const int msrow = j * 64 + w * 16 + lr;
            bfr[j] = *(const s16x8*)((const char*)MS + (size_t)msrow * 512 + kb);
        }
        #pragma unroll
        for (int rf = 0; rf < 4; ++rf)
            #pragma unroll
            for (int j = 0; j < 2; ++j)
                acc[rf][j] = __builtin_amdgcn_mfma_f32_16x16x32_bf16(
                    areg[rf], bfr[j], acc[rf][j], 0, 0, 0);
    }

    // ---- S1 epilogue: scores f32 + per-block softmax partials ----
    {
        const int a = w * 16 + lr;
        const float bv = cbias[a];
        float mx = -1e30f;
        #pragma unroll
        for (int rf = 0; rf < 4; ++rf)
            #pragma unroll
            for (int r = 0; r < 4; ++r) {
                const float v = acc[rf][0][r] + bv;
                S1T[(m0 + rf * 16 + lq * 4 + r) * 64 + a] = v;
                mx = fmaxf(mx, v);
            }
        mx = fmaxf(mx, __shfl_xor(mx, 16));
        mx = fmaxf(mx, __shfl_xor(mx, 32));
        float sm = 0.f;
        #pragma unroll
        for (int rf = 0; rf < 4; ++rf)
            #pragma unroll
            for (int r = 0; r < 4; ++r)
                sm += __expf(acc[rf][0][r] + bv - mx);
        sm += __shfl_xor(sm, 16);
        sm += __shfl_xor(sm, 32);
        if (lq == 0) {
            mpart[(size_t)blockIdx.x * 64 + a] = mx;
            lpart[(size_t)blockIdx.x * 64 + a] = sm;
        }
    }

    // ---- S2: scores -> LDS transpose (f32, pitch 68 floats over As) ----
    __syncthreads();                 // all As MFMA reads done
    {
        float* SC = (float*)As;
        const int a = w * 16 + lr;
        const float bv = cbias[64 + a];
        #pragma unroll
        for (int rf = 0; rf < 4; ++rf)
            #pragma unroll
            for (int r = 0; r < 4; ++r) {
                const int n = rf * 16 + lq * 4 + r;
                SC[n * 68 + a] = acc[rf][1][r] + bv;
            }
    }
    __syncthreads();
    // ---- 4-lane-group softmax over 64 agents, write P2 bf16 swizzled ----
    {
        const float* SC = (const float*)As;
        const int t4 = lane >> 2, q = lane & 3;
        const int nl = w * 16 + t4;
        f32x4 sv[4];
        #pragma unroll
        for (int j = 0; j < 4; ++j) sv[j] = *(const f32x4*)&SC[nl * 68 + q * 16 + j * 4];
        float mx = -1e30f;
        #pragma unroll
        for (int j = 0; j < 4; ++j)
            #pragma unroll
            for (int e = 0; e < 4; ++e) mx = fmaxf(mx, sv[j][e]);
        mx = fmaxf(mx, __shfl_xor(mx, 1));
        mx = fmaxf(mx, __shfl_xor(mx, 2));
        float p[16];
        float sm = 0.f;
        #pragma unroll
        for (int j = 0; j < 4; ++j)
            #pragma unroll
            for (int e = 0; e < 4; ++e) {
                p[j * 4 + e] = __expf(sv[j][e] - mx);
                sm += p[j * 4 + e];
            }
        sm += __shfl_xor(sm, 1);
        sm += __shfl_xor(sm, 2);
        const float rs = 1.f / sm;
        s16x8 o0, o1;
        #pragma unroll
        for (int e = 0; e < 8; ++e) o0[e] = (short)f2bf(p[e] * rs);
        #pragma unroll
        for (int e = 0; e < 8; ++e) o1[e] = (short)f2bf(p[8 + e] * rs);
        const int swz = (nl & 7) << 4;
        char* row = (char*)P2 + (m0 + nl) * 128;
        *(s16x8*)(row + ((q * 32) ^ swz)) = o0;
        *(s16x8*)(row + ((q * 32 + 16) ^ swz)) = o1;
    }
}

// ---------------------------------------------------------------------------
// y = attn1 @ x via MFMA (partials over 16 n-chunks of 512), stage-1 stat
// combine fused (scratch LDS over XT before staging).
// ---------------------------------------------------------------------------
__global__ __launch_bounds__(256) void pv_mfma2(
    const float* __restrict__ S1T,
    const float* __restrict__ x,
    const float* __restrict__ mpart,
    const float* __restrict__ lpart,
    float* __restrict__ y_part)
{
    __shared__ alignas(16) unsigned short P_lds[64 * 128];   // [a][n] 16KB
    __shared__ alignas(16) unsigned short XT[128 * 136];     // [d][136n] (pad row)
    const int tid = threadIdx.x, lane = tid & 63, w = tid >> 6;
    const int lr = lane & 15, lq = lane >> 4;
    const int c = blockIdx.x, dh = blockIdx.y, b = blockIdx.z;
    const int a4 = (tid & 15) * 4;

    // ---- fused s1_combine ----
    f32x4 m4, l4;
    {
        float* scratch = (float*)XT;
        const int a = tid & 63, s4 = tid >> 6;
        const size_t bb = (size_t)b * 128;
        float M = -1e30f;
        for (int cc = s4; cc < 128; cc += 4)
            M = fmaxf(M, mpart[(bb + cc) * 64 + a]);
        float L = 0.f;
        for (int cc = s4; cc < 128; cc += 4) {
            const size_t idx = (bb + cc) * 64 + a;
            L += lpart[idx] * __expf(mpart[idx] - M);
        }
        scratch[tid] = M;
        scratch[256 + tid] = L;
        __syncthreads();
        if (tid < 64) {
            float Mm = scratch[tid];
            #pragma unroll
            for (int ss = 1; ss < 4; ++ss) Mm = fmaxf(Mm, scratch[ss * 64 + tid]);
            float Ll = 0.f;
            #pragma unroll
            for (int ss = 0; ss < 4; ++ss)
                Ll += scratch[256 + ss * 64 + tid] * __expf(scratch[ss * 64 + tid] - Mm);
            scratch[512 + tid] = Mm;
            scratch[576 + tid] = 1.0f / Ll;
        }
        __syncthreads();
        #pragma unroll
        for (int j = 0; j < 4; ++j) {
            m4[j] = scratch[512 + a4 + j];
            l4[j] = scratch[576 + a4 + j];
        }
        __syncthreads();
    }

    f32x4 acc[4][2];
    const f32x4 zero = {0.f, 0.f, 0.f, 0.f};
    #pragma unroll
    for (int rf = 0; rf < 4; ++rf)
        #pragma unroll
        for (int cf = 0; cf < 2; ++cf)
            acc[rf][cf] = zero;

    for (int kt = 0; kt < 4; ++kt) {
        const size_t ng0 = (size_t)b * 8192 + c * 512 + kt * 128;
        #pragma unroll
        for (int pass = 0; pass < 4; ++pass) {
            const int np = 2 * (tid >> 4) + pass * 32;
            const float* s = S1T + (ng0 + np) * 64 + a4;
            f32x4 s0 = *(const f32x4*)s;
            f32x4 s1 = *(const f32x4*)(s + 64);
            #pragma unroll
            for (int j = 0; j < 4; ++j) {
                const int a = a4 + j;
                const float p0 = __expf(s0[j] - m4[j]) * l4[j];
                const float p1 = __expf(s1[j] - m4[j]) * l4[j];
                const unsigned int pk = (unsigned int)f2bf(p0) | ((unsigned int)f2bf(p1) << 16);
                *(unsigned int*)((char*)P_lds + a * 256 + ((np * 2) ^ (((a >> 1) & 7) << 4))) = pk;
            }
        }
        {
            const int nh = tid >> 2;
            const int dq = tid & 3;
            const float* xbase = x + (ng0 + 2 * nh) * 256 + dh * 128;
            #pragma unroll
            for (int pass = 0; pass < 8; ++pass) {
                const int dl0 = pass * 16 + dq * 4;
                f32x4 xa = *(const f32x4*)(xbase + dl0);
                f32x4 xb = *(const f32x4*)(xbase + 256 + dl0);
                #pragma unroll
                for (int jj = 0; jj < 4; ++jj) {
                    const unsigned int pk = (unsigned int)f2bf(xa[jj]) | ((unsigned int)f2bf(xb[jj]) << 16);
                    *(unsigned int*)((char*)XT + (dl0 + jj) * 272 + nh * 4) = pk;
                }
            }
        }
        __syncthreads();
        #pragma unroll
        for (int ks = 0; ks < 4; ++ks) {
            const int kbn = ks * 64 + lq * 16;
            s16x8 af[4], bfv[2];
            #pragma unroll
            for (int rf = 0; rf < 4; ++rf) {
                const int row = rf * 16 + lr;
                af[rf] = *(const s16x8*)((const char*)P_lds + row * 256 + (kbn ^ (((row >> 1) & 7) << 4)));
            }
            #pragma unroll
            for (int cf = 0; cf < 2; ++cf) {
                const int dl = w * 32 + cf * 16 + lr;
                bfv[cf] = *(const s16x8*)((const char*)XT + dl * 272 + kbn);
            }
            #pragma unroll
            for (int rf = 0; rf < 4; ++rf)
                #pragma unroll
                for (int cf = 0; cf < 2; ++cf)
                    acc[rf][cf] = __builtin_amdgcn_mfma_f32_16x16x32_bf16(
                        af[rf], bfv[cf], acc[rf][cf], 0, 0, 0);
        }
        __syncthreads();
    }
    #pragma unroll
    for (int rf = 0; rf < 4; ++rf)
        #pragma unroll
        for (int cf = 0; cf < 2; ++cf)
            #pragma unroll
            for (int r = 0; r < 4; ++r) {
                const int a = rf * 16 + lq * 4 + r;
                const int d = dh * 128 + w * 32 + cf * 16 + lr;
                y_part[(((size_t)b * 16 + c) * 64 + a) * 256 + d] = acc[rf][cf][r];
            }
}

// ---------------------------------------------------------------------------
// chain_fused (grid 8, one block per batch): reduce y_part (16 chunks) ->
// LDS bf16, then u = ((y@Wv^T+bv)@W1^T+b1)@W2^T+b2 with intermediates in
// LDS ping-pong buffers; weights from pre-converted bf16 Wb.
// ---------------------------------------------------------------------------
__global__ __launch_bounds__(256) void chain_fused(
    const float* __restrict__ y_part,
    const unsigned short* __restrict__ Wb,     // [3][256][256] bf16
    const float* __restrict__ b_qkv,
    const float* __restrict__ b_fc1,
    const float* __restrict__ b_fc2,
    float* __restrict__ uu)
{
    __shared__ alignas(16) unsigned short A0[64 * 256];   // 32KB
    __shared__ alignas(16) unsigned short A1[64 * 256];   // 32KB
    const int tid = threadIdx.x, lane = tid & 63, w = tid >> 6;
    const int lr = lane & 15, lq = lane >> 4;
    const int b = blockIdx.x;

    // ---- reduce y_part[b][16][64][256] -> A0 bf16 (swizzled rows) ----
    {
        const float* yp = y_part + (size_t)b * 16 * 64 * 256;
        f32x4 r16[16];
        const f32x4 zero = {0.f, 0.f, 0.f, 0.f};
        #pragma unroll
        for (int j = 0; j < 16; ++j) r16[j] = zero;
        for (int c = 0; c < 16; ++c) {
            const float* base = yp + (size_t)c * 16384 + tid * 4;
            #pragma unroll
            for (int j = 0; j < 16; ++j)
                r16[j] += *(const f32x4*)(base + j * 1024);
        }
        #pragma unroll
        for (int j = 0; j < 16; ++j) {
            const int a = j * 4 + (tid >> 6);
            const int d0 = (tid & 63) * 4;
            s16x4 pk;
            #pragma unroll
            for (int e = 0; e < 4; ++e) pk[e] = (short)f2bf(r16[j][e]);
            *(s16x4*)((char*)A0 + a * 512 + ((d0 * 2) ^ ((a & 7) << 4))) = pk;
        }
    }
    __syncthreads();

    // ---- 3 GEMM stages, LDS ping-pong ----
    unsigned short* bufA = A0;
    unsigned short* bufB = A1;
    for (int s = 0; s < 3; ++s) {
        const unsigned short* W = Wb + (size_t)s * 65536;
        const float* bias = (s == 0) ? (b_qkv + 512) : (s == 1) ? b_fc1 : b_fc2;
        f32x4 acc[4][4];
        const f32x4 zero = {0.f, 0.f, 0.f, 0.f};
        #pragma unroll
        for (int rf = 0; rf < 4; ++rf)
            #pragma unroll
            for (int cf = 0; cf < 4; ++cf)
                acc[rf][cf] = zero;
        #pragma unroll
        for (int ks = 0; ks < 8; ++ks) {
            const int kb = ks * 64 + lq * 16;
            s16x8 af[4], bf[4];
            #pragma unroll
            for (int rf = 0; rf < 4; ++rf) {
                const int row = rf * 16 + lr;
                af[rf] = *(const s16x8*)((const char*)bufA + row * 512 + (kb ^ ((row & 7) << 4)));
            }
            #pragma unroll
            for (int cf = 0; cf < 4; ++cf) {
                const int col = w * 64 + cf * 16 + lr;
                bf[cf] = *(const s16x8*)((const char*)W + (size_t)col * 512 + kb);
            }
            #pragma unroll
            for (int rf = 0; rf < 4; ++rf)
                #pragma unroll
                for (int cf = 0; cf < 4; ++cf)
                    acc[rf][cf] = __builtin_amdgcn_mfma_f32_16x16x32_bf16(
                        af[rf], bf[cf], acc[rf][cf], 0, 0, 0);
        }
        if (s < 2) {
            #pragma unroll
            for (int cf = 0; cf < 4; ++cf) {
                const int col = w * 64 + cf * 16 + lr;
                const float bv = bias[col];
                #pragma unroll
                for (int rf = 0; rf < 4; ++rf)
                    #pragma unroll
                    for (int r = 0; r < 4; ++r) {
                        const int a = rf * 16 + lq * 4 + r;
                        *(unsigned short*)((char*)bufB + a * 512 + ((col * 2) ^ ((a & 7) << 4)))
                            = f2bf(acc[rf][cf][r] + bv);
                    }
            }
            __syncthreads();
            unsigned short* t = bufA; bufA = bufB; bufB = t;
        } else {
            #pragma unroll
            for (int cf = 0; cf < 4; ++cf) {
                const int col = w * 64 + cf * 16 + lr;
                const float bv = bias[col];
                #pragma unroll
                for (int rf = 0; rf < 4; ++rf)
                    #pragma unroll
                    for (int r = 0; r < 4; ++r) {
                        const int a = rf * 16 + lq * 4 + r;
                        uu[((size_t)b * 64 + a) * 256 + col] = acc[rf][cf][r] + bv;
                    }
            }
        }
    }
}

// ---------------------------------------------------------------------------
// Stage-2 fused: P2 (finalized bf16 probs, pre-swizzled) copy -> LDS, PV via
// MFMA (A = uT rows d, B = P rows n), residual + RMSNorm, f32x4 hot path.
// ---------------------------------------------------------------------------
__global__ __launch_bounds__(256) void stage2_final(const unsigned short* __restrict__ P2,
                                                    const float* __restrict__ uu,
                                                    const float* __restrict__ x,
                                                    const float* __restrict__ nscale,
                                                    float* __restrict__ out)
{
    __shared__ alignas(16) unsigned short uT[256 * 64];  // [d][a] pitch 128B, swz
    __shared__ alignas(16) unsigned short P[64 * 64];    // [n][a] pitch 128B, swz
    __shared__ float ssq[4][64];
    const int tid = threadIdx.x, lane = tid & 63, w = tid >> 6;
    const int lr = lane & 15, lq = lane >> 4;
    const int b = blockIdx.x >> 7;
    const long n0 = (long)blockIdx.x * 64;

    {
        const int pr = tid >> 3;      // a-pair 0..31
        const int sub = tid & 7;
        const float* u0 = uu + ((size_t)b * 64 + 2 * pr) * 256;
        #pragma unroll
        for (int pass = 0; pass < 8; ++pass) {
            const int d0 = pass * 32 + sub * 4;
            f32x4 ua = *(const f32x4*)(u0 + d0);
            f32x4 ub = *(const f32x4*)(u0 + 256 + d0);
            #pragma unroll
            for (int jj = 0; jj < 4; ++jj) {
                const int d = d0 + jj;
                const unsigned int pk = (unsigned int)f2bf(ua[jj]) | ((unsigned int)f2bf(ub[jj]) << 16);
                *(unsigned int*)((char*)uT + d * 128 + ((pr * 4) ^ ((d & 7) << 4))) = pk;
            }
        }
    }
    {
        const int row = tid & 63, seg = tid >> 6;   // 4 segs x 32B
        const char* src = (const char*)P2 + (n0 + row) * 128 + seg * 32;
        s16x8 v0 = *(const s16x8*)src;
        s16x8 v1 = *(const s16x8*)(src + 16);
        *(s16x8*)((char*)P + row * 128 + seg * 32) = v0;
        *(s16x8*)((char*)P + row * 128 + seg * 32 + 16) = v1;
    }
    __syncthreads();

    f32x4 acc[4][4];
    const f32x4 zero = {0.f, 0.f, 0.f, 0.f};
    #pragma unroll
    for (int rf = 0; rf < 4; ++rf)
        #pragma unroll
        for (int cf = 0; cf < 4; ++cf)
            acc[rf][cf] = zero;
    #pragma unroll
    for (int ks = 0; ks < 2; ++ks) {
        const int kb = ks * 64 + lq * 16;
        s16x8 af[4], bfv[4];
        #pragma unroll
        for (int rf = 0; rf < 4; ++rf) {
            const int dR = w * 64 + rf * 16 + lr;
            af[rf] = *(const s16x8*)((const char*)uT + dR * 128 + (kb ^ ((dR & 7) << 4)));
        }
        #pragma unroll
        for (int cf = 0; cf < 4; ++cf) {
            const int nR = cf * 16 + lr;
            bfv[cf] = *(const s16x8*)((const char*)P + nR * 128 + (kb ^ ((nR & 7) << 4)));
        }
        #pragma unroll
        for (int rf = 0; rf < 4; ++rf)
            #pragma unroll
            for (int cf = 0; cf < 4; ++cf)
                acc[rf][cf] = __builtin_amdgcn_mfma_f32_16x16x32_bf16(
                    af[rf], bfv[cf], acc[rf][cf], 0, 0, 0);
    }

    float part[4] = {0.f, 0.f, 0.f, 0.f};
    #pragma unroll
    for (int cf = 0; cf < 4; ++cf) {
        const long n = n0 + cf * 16 + lr;
        #pragma unroll
        for (int rf = 0; rf < 4; ++rf) {
            const int d0 = w * 64 + rf * 16 + lq * 4;
            const f32x4 xr = *(const f32x4*)&x[n * 256 + d0];
            acc[rf][cf] += xr;
            part[cf] += acc[rf][cf][0] * acc[rf][cf][0] + acc[rf][cf][1] * acc[rf][cf][1]
                      + acc[rf][cf][2] * acc[rf][cf][2] + acc[rf][cf][3] * acc[rf][cf][3];
        }
    }
    #pragma unroll
    for (int cf = 0; cf < 4; ++cf) {
        float s = part[cf];
        s += __shfl_xor(s, 16);
        s += __shfl_xor(s, 32);
        if (lq == 0) ssq[w][cf * 16 + lr] = s;
    }
    __syncthreads();

    #pragma unroll
    for (int cf = 0; cf < 4; ++cf) {
        const int tokl = cf * 16 + lr;
        const float tot = ssq[0][tokl] + ssq[1][tokl] + ssq[2][tokl] + ssq[3][tokl];
        const float inv = 1.f / (sqrtf(tot) * 0.0625f + 1e-8f);
        const long n = n0 + tokl;
        #pragma unroll
        for (int rf = 0; rf < 4; ++rf) {
            const int d0 = w * 64 + rf * 16 + lq * 4;
            const f32x4 sc4 = *(const f32x4*)&nscale[d0];
            f32x4 o = sc4 * acc[rf][cf] * inv;
            *(f32x4*)&out[n * 256 + d0] = o;
        }
    }
}

// ---------------------------------------------------------------------------
extern "C" void kernel_launch(void* const* d_in, const int* in_sizes, int n_in,
                              void* d_out, int out_size, void* d_ws, size_t ws_size,
                              hipStream_t stream)
{
    const float* agent   = (const float*)d_in[0];
    const float* x       = (const float*)d_in[1];
    const float* W_qkv   = (const float*)d_in[2];
    const float* b_qkv   = (const float*)d_in[3];
    const float* W_agent = (const float*)d_in[4];
    const float* b_agent = (const float*)d_in[5];
    const float* W_fc1   = (const float*)d_in[6];
    const float* b_fc1   = (const float*)d_in[7];
    const float* W_fc2   = (const float*)d_in[8];
    const float* b_fc2   = (const float*)d_in[9];
    const float* nscale  = (const float*)d_in[10];
    float* out = (float*)d_out;

    char* wsp = (char*)d_ws;
    size_t off = 0;
    auto alloc = [&](size_t n) { void* p = wsp + off; off += (n + 255) & ~(size_t)255; return p; };

    unsigned short* MS = (unsigned short*)alloc(128UL * 256 * 2);
    float*  cbias  = (float*)alloc(128UL * 4);
    unsigned short* Wb = (unsigned short*)alloc(3UL * 256 * 256 * 2);
    float*  S1T    = (float*)alloc(65536UL * 64 * 4);              // [n][a] f32
    unsigned short* P2 = (unsigned short*)alloc(65536UL * 64 * 2); // [n][a] bf16 swz
    float*  mpart  = (float*)alloc(1024UL * 64 * 4);
    float*  lpart  = (float*)alloc(1024UL * 64 * 4);
    float*  y_part = (float*)alloc(8UL * 16 * 64 * 256 * 4);
    float*  uu     = (float*)alloc(512UL * 256 * 4);

    // 1. MS + cbias (agent proj fused) + bf16 weight conversion
    build_M2<<<320, 256, 0, stream>>>(W_qkv, b_qkv, agent, W_agent, b_agent,
                                      W_fc1, W_fc2, MS, cbias, Wb);
    // 2. streaming scores: S1T f32 + stage-1 partials; P2 = finalized stage-2 probs
    xproj2<<<1024, 256, 0, stream>>>(x, MS, cbias, S1T, P2, mpart, lpart);
    // 3. y = attn1 @ x via MFMA (stat combine fused)
    pv_mfma2<<<dim3(16, 2, 8), 256, 0, stream>>>(S1T, x, mpart, lpart, y_part);
    // 4. reduce + full fc chain in one kernel (LDS-resident intermediates)
    chain_fused<<<8, 256, 0, stream>>>(y_part, Wb, b_qkv, b_fc1, b_fc2, uu);
    // 5. P2 copy + PV MFMA + residual + rmsnorm
    stage2_final<<<1024, 256, 0, stream>>>(P2, uu, x, nscale, out);
}

// Round 10
// 121.094 us; speedup vs baseline: 1.1474x; 1.1474x over previous
//
#include <hip/hip_runtime.h>
#include <hip/hip_bf16.h>

typedef __attribute__((ext_vector_type(4))) float f32x4;
typedef __attribute__((ext_vector_type(8))) short s16x8;
typedef __attribute__((ext_vector_type(4))) short s16x4;

__device__ __forceinline__ unsigned short f2bf(float f) {
    unsigned int u; __builtin_memcpy(&u, &f, 4);
    u += 0x7fffu + ((u >> 16) & 1u);
    return (unsigned short)(u >> 16);
}
__device__ __forceinline__ float bf2f(unsigned short h) {
    unsigned int u = ((unsigned int)h) << 16;
    float f; __builtin_memcpy(&f, &u, 4);
    return f;
}
__device__ __forceinline__ s16x8 pack8(f32x4 a, f32x4 b) {
    s16x8 r;
    r[0] = (short)f2bf(a[0]); r[1] = (short)f2bf(a[1]);
    r[2] = (short)f2bf(a[2]); r[3] = (short)f2bf(a[3]);
    r[4] = (short)f2bf(b[0]); r[5] = (short)f2bf(b[1]);
    r[6] = (short)f2bf(b[2]); r[7] = (short)f2bf(b[3]);
    return r;
}

// ---------------------------------------------------------------------------
// build_M2 (grid 320):
//   blocks 0..127  : MS [128][256] bf16 + cbias[128] with agent proj fused
//   blocks 128..319: Wb [3][256][256] bf16 = {W_v, W_fc1, W_fc2} converted
// ---------------------------------------------------------------------------
__global__ __launch_bounds__(256) void build_M2(
    const float* __restrict__ W_qkv, const float* __restrict__ b_qkv,
    const float* __restrict__ agent, const float* __restrict__ W_agent,
    const float* __restrict__ b_agent,
    const float* __restrict__ W_fc1, const float* __restrict__ W_fc2,
    unsigned short* __restrict__ MS, float* __restrict__ cbias,
    unsigned short* __restrict__ Wb)
{
    const int i = blockIdx.x;
    const int t = threadIdx.x;
    if (i >= 128) {
        const int R0 = (i - 128) * 4;
        #pragma unroll
        for (int rr = 0; rr < 4; ++rr) {
            const int R = R0 + rr;
            const float* src = (R < 256) ? W_qkv + (size_t)(512 + R) * 256
                             : (R < 512) ? W_fc1 + (size_t)(R - 256) * 256
                                         : W_fc2 + (size_t)(R - 512) * 256;
            Wb[(size_t)R * 256 + t] = f2bf(src[t]);
        }
        return;
    }
    __shared__ float ag[256];
    __shared__ float qs[256];
    const int a = i & 63;
    const bool isS1 = (i < 64);
    ag[t] = agent[(size_t)a * 256 + t];
    __syncthreads();
    const int tp = isS1 ? t : 256 + t;
    {
        const float* wr = W_agent + (size_t)tp * 256;
        float q = 0.f;
        #pragma unroll 4
        for (int d = 0; d < 256; d += 4) {
            f32x4 wv = *(const f32x4*)(wr + d);
            q += ag[d] * wv[0] + ag[d + 1] * wv[1] + ag[d + 2] * wv[2] + ag[d + 3] * wv[3];
        }
        qs[t] = (q + b_agent[tp]) * 0.0625f;
    }
    __syncthreads();
    const float* W  = W_qkv + (isS1 ? 256 * 256 : 0);   // W_k : W_q
    const float* bb = b_qkv + (isS1 ? 256 : 0);
    float acc = 0.f, cb = 0.f;
    for (int dout = 0; dout < 256; ++dout) {
        const float q = qs[dout];
        acc += q * W[(size_t)dout * 256 + t];
        cb  += q * bb[dout];
    }
    MS[i * 256 + t] = f2bf(acc);
    if (t == 0) cbias[i] = cb;
}

// ---------------------------------------------------------------------------
// Streaming scores (R9 proven): per 64-token block:
//   S1T[n][a] f32 + stage-1 softmax partials;
//   P2[n][a] bf16 = FINALIZED stage-2 probs (swizzled rows).
// ---------------------------------------------------------------------------
__global__ __launch_bounds__(256) void xproj2(
    const float* __restrict__ x,
    const unsigned short* __restrict__ MS,
    const float* __restrict__ cbias,
    float* __restrict__ S1T,
    unsigned short* __restrict__ P2,
    float* __restrict__ mpart, float* __restrict__ lpart)
{
    __shared__ alignas(16) unsigned short As[64 * 256];   // 32KB; reused for S2 scores
    const int tid = threadIdx.x, lane = tid & 63, w = tid >> 6;
    const int lr = lane & 15, lq = lane >> 4;
    const long m0 = (long)blockIdx.x * 64;

    {
        const int k0 = (tid & 31) * 8;
        #pragma unroll
        for (int j = 0; j < 8; ++j) {
            const int row = (tid >> 5) + j * 8;
            const float* s = x + (m0 + row) * 256 + k0;
            f32x4 f0 = *(const f32x4*)s;
            f32x4 f1 = *(const f32x4*)(s + 4);
            *(s16x8*)((char*)As + row * 512 + ((k0 * 2) ^ ((row & 7) << 4))) = pack8(f0, f1);
        }
    }
    __syncthreads();

    f32x4 acc[4][2];
    const f32x4 zero = {0.f, 0.f, 0.f, 0.f};
    #pragma unroll
    for (int rf = 0; rf < 4; ++rf)
        #pragma unroll
        for (int j = 0; j < 2; ++j)
            acc[rf][j] = zero;

    #pragma unroll
    for (int ks = 0; ks < 8; ++ks) {
        const int kb = ks * 64 + lq * 16;
        s16x8 areg[4];
        #pragma unroll
        for (int rf = 0; rf < 4; ++rf) {
            const int row = rf * 16 + lr;
            areg[rf] = *(const s16x8*)((const char*)As + row * 512 + (kb ^ ((row & 7) << 4)));
        }
        s16x8 bfr[2];
        #pragma unroll
        for (int j = 0; j < 2; ++j) {
            const int msrow = j * 64 + w * 16 + lr;
            bfr[j] = *(const s16x8*)((const char*)MS + (size_t)msrow * 512 + kb);
        }
        #pragma unroll
        for (int rf = 0; rf < 4; ++rf)
            #pragma unroll
            for (int j = 0; j < 2; ++j)
                acc[rf][j] = __builtin_amdgcn_mfma_f32_16x16x32_bf16(
                    areg[rf], bfr[j], acc[rf][j], 0, 0, 0);
    }

    // ---- S1 epilogue: scores f32 + per-block softmax partials ----
    {
        const int a = w * 16 + lr;
        const float bv = cbias[a];
        float mx = -1e30f;
        #pragma unroll
        for (int rf = 0; rf < 4; ++rf)
            #pragma unroll
            for (int r = 0; r < 4; ++r) {
                const float v = acc[rf][0][r] + bv;
                S1T[(m0 + rf * 16 + lq * 4 + r) * 64 + a] = v;
                mx = fmaxf(mx, v);
            }
        mx = fmaxf(mx, __shfl_xor(mx, 16));
        mx = fmaxf(mx, __shfl_xor(mx, 32));
        float sm = 0.f;
        #pragma unroll
        for (int rf = 0; rf < 4; ++rf)
            #pragma unroll
            for (int r = 0; r < 4; ++r)
                sm += __expf(acc[rf][0][r] + bv - mx);
        sm += __shfl_xor(sm, 16);
        sm += __shfl_xor(sm, 32);
        if (lq == 0) {
            mpart[(size_t)blockIdx.x * 64 + a] = mx;
            lpart[(size_t)blockIdx.x * 64 + a] = sm;
        }
    }

    // ---- S2: scores -> LDS transpose (f32, pitch 68 floats over As) ----
    __syncthreads();                 // all As MFMA reads done
    {
        float* SC = (float*)As;
        const int a = w * 16 + lr;
        const float bv = cbias[64 + a];
        #pragma unroll
        for (int rf = 0; rf < 4; ++rf)
            #pragma unroll
            for (int r = 0; r < 4; ++r) {
                const int n = rf * 16 + lq * 4 + r;
                SC[n * 68 + a] = acc[rf][1][r] + bv;
            }
    }
    __syncthreads();
    // ---- 4-lane-group softmax over 64 agents, write P2 bf16 swizzled ----
    {
        const float* SC = (const float*)As;
        const int t4 = lane >> 2, q = lane & 3;
        const int nl = w * 16 + t4;
        f32x4 sv[4];
        #pragma unroll
        for (int j = 0; j < 4; ++j) sv[j] = *(const f32x4*)&SC[nl * 68 + q * 16 + j * 4];
        float mx = -1e30f;
        #pragma unroll
        for (int j = 0; j < 4; ++j)
            #pragma unroll
            for (int e = 0; e < 4; ++e) mx = fmaxf(mx, sv[j][e]);
        mx = fmaxf(mx, __shfl_xor(mx, 1));
        mx = fmaxf(mx, __shfl_xor(mx, 2));
        float p[16];
        float sm = 0.f;
        #pragma unroll
        for (int j = 0; j < 4; ++j)
            #pragma unroll
            for (int e = 0; e < 4; ++e) {
                p[j * 4 + e] = __expf(sv[j][e] - mx);
                sm += p[j * 4 + e];
            }
        sm += __shfl_xor(sm, 1);
        sm += __shfl_xor(sm, 2);
        const float rs = 1.f / sm;
        s16x8 o0, o1;
        #pragma unroll
        for (int e = 0; e < 8; ++e) o0[e] = (short)f2bf(p[e] * rs);
        #pragma unroll
        for (int e = 0; e < 8; ++e) o1[e] = (short)f2bf(p[8 + e] * rs);
        const int swz = (nl & 7) << 4;
        char* row = (char*)P2 + (m0 + nl) * 128;
        *(s16x8*)(row + ((q * 32) ^ swz)) = o0;
        *(s16x8*)(row + ((q * 32 + 16) ^ swz)) = o1;
    }
}

// ---------------------------------------------------------------------------
// y = attn1 @ x via MFMA (R8 proven: partials over 32 n-chunks of 256,
// grid (32,2,8) = 2 blocks/CU), stage-1 stat combine fused.
// ---------------------------------------------------------------------------
__global__ __launch_bounds__(256) void pv_mfma2(
    const float* __restrict__ S1T,
    const float* __restrict__ x,
    const float* __restrict__ mpart,
    const float* __restrict__ lpart,
    float* __restrict__ y_part)
{
    __shared__ alignas(16) unsigned short P_lds[64 * 128];   // [a][n] 16KB
    __shared__ alignas(16) unsigned short XT[128 * 136];     // [d][136n] (pad row)
    const int tid = threadIdx.x, lane = tid & 63, w = tid >> 6;
    const int lr = lane & 15, lq = lane >> 4;
    const int c = blockIdx.x, dh = blockIdx.y, b = blockIdx.z;
    const int a4 = (tid & 15) * 4;

    // ---- fused s1_combine ----
    f32x4 m4, l4;
    {
        float* scratch = (float*)XT;
        const int a = tid & 63, s4 = tid >> 6;
        const size_t bb = (size_t)b * 128;
        float M = -1e30f;
        for (int cc = s4; cc < 128; cc += 4)
            M = fmaxf(M, mpart[(bb + cc) * 64 + a]);
        float L = 0.f;
        for (int cc = s4; cc < 128; cc += 4) {
            const size_t idx = (bb + cc) * 64 + a;
            L += lpart[idx] * __expf(mpart[idx] - M);
        }
        scratch[tid] = M;
        scratch[256 + tid] = L;
        __syncthreads();
        if (tid < 64) {
            float Mm = scratch[tid];
            #pragma unroll
            for (int ss = 1; ss < 4; ++ss) Mm = fmaxf(Mm, scratch[ss * 64 + tid]);
            float Ll = 0.f;
            #pragma unroll
            for (int ss = 0; ss < 4; ++ss)
                Ll += scratch[256 + ss * 64 + tid] * __expf(scratch[ss * 64 + tid] - Mm);
            scratch[512 + tid] = Mm;
            scratch[576 + tid] = 1.0f / Ll;
        }
        __syncthreads();
        #pragma unroll
        for (int j = 0; j < 4; ++j) {
            m4[j] = scratch[512 + a4 + j];
            l4[j] = scratch[576 + a4 + j];
        }
        __syncthreads();
    }

    f32x4 acc[4][2];
    const f32x4 zero = {0.f, 0.f, 0.f, 0.f};
    #pragma unroll
    for (int rf = 0; rf < 4; ++rf)
        #pragma unroll
        for (int cf = 0; cf < 2; ++cf)
            acc[rf][cf] = zero;

    for (int kt = 0; kt < 2; ++kt) {
        const size_t ng0 = (size_t)b * 8192 + c * 256 + kt * 128;
        #pragma unroll
        for (int pass = 0; pass < 4; ++pass) {
            const int np = 2 * (tid >> 4) + pass * 32;
            const float* s = S1T + (ng0 + np) * 64 + a4;
            f32x4 s0 = *(const f32x4*)s;
            f32x4 s1 = *(const f32x4*)(s + 64);
            #pragma unroll
            for (int j = 0; j < 4; ++j) {
                const int a = a4 + j;
                const float p0 = __expf(s0[j] - m4[j]) * l4[j];
                const float p1 = __expf(s1[j] - m4[j]) * l4[j];
                const unsigned int pk = (unsigned int)f2bf(p0) | ((unsigned int)f2bf(p1) << 16);
                *(unsigned int*)((char*)P_lds + a * 256 + ((np * 2) ^ (((a >> 1) & 7) << 4))) = pk;
            }
        }
        {
            const int nh = tid >> 2;
            const int dq = tid & 3;
            const float* xbase = x + (ng0 + 2 * nh) * 256 + dh * 128;
            #pragma unroll
            for (int pass = 0; pass < 8; ++pass) {
                const int dl0 = pass * 16 + dq * 4;
                f32x4 xa = *(const f32x4*)(xbase + dl0);
                f32x4 xb = *(const f32x4*)(xbase + 256 + dl0);
                #pragma unroll
                for (int jj = 0; jj < 4; ++jj) {
                    const unsigned int pk = (unsigned int)f2bf(xa[jj]) | ((unsigned int)f2bf(xb[jj]) << 16);
                    *(unsigned int*)((char*)XT + (dl0 + jj) * 272 + nh * 4) = pk;
                }
            }
        }
        __syncthreads();
        #pragma unroll
        for (int ks = 0; ks < 4; ++ks) {
            const int kbn = ks * 64 + lq * 16;
            s16x8 af[4], bfv[2];
            #pragma unroll
            for (int rf = 0; rf < 4; ++rf) {
                const int row = rf * 16 + lr;
                af[rf] = *(const s16x8*)((const char*)P_lds + row * 256 + (kbn ^ (((row >> 1) & 7) << 4)));
            }
            #pragma unroll
            for (int cf = 0; cf < 2; ++cf) {
                const int dl = w * 32 + cf * 16 + lr;
                bfv[cf] = *(const s16x8*)((const char*)XT + dl * 272 + kbn);
            }
            #pragma unroll
            for (int rf = 0; rf < 4; ++rf)
                #pragma unroll
                for (int cf = 0; cf < 2; ++cf)
                    acc[rf][cf] = __builtin_amdgcn_mfma_f32_16x16x32_bf16(
                        af[rf], bfv[cf], acc[rf][cf], 0, 0, 0);
        }
        __syncthreads();
    }
    #pragma unroll
    for (int rf = 0; rf < 4; ++rf)
        #pragma unroll
        for (int cf = 0; cf < 2; ++cf)
            #pragma unroll
            for (int r = 0; r < 4; ++r) {
                const int a = rf * 16 + lq * 4 + r;
                const int d = dh * 128 + w * 32 + cf * 16 + lr;
                y_part[(((size_t)b * 32 + c) * 64 + a) * 256 + d] = acc[rf][cf][r];
            }
}

// ---------------------------------------------------------------------------
// chain_fused (grid 4 x 8 = 32 blocks): the fc chain is ROW-INDEPENDENT, so
// each block owns 16 agent rows of one batch: reduce y_part (32 chunks) ->
// 8KB LDS bf16 tile, then 3 MFMA stages (A = 16 rows, B = Wb cols) with
// LDS ping-pong.  u written f32.
// ---------------------------------------------------------------------------
__global__ __launch_bounds__(256) void chain_fused(
    const float* __restrict__ y_part,          // [8][32][64][256]
    const unsigned short* __restrict__ Wb,     // [3][256][256] bf16
    const float* __restrict__ b_qkv,
    const float* __restrict__ b_fc1,
    const float* __restrict__ b_fc2,
    float* __restrict__ uu)
{
    __shared__ alignas(16) unsigned short A0[16 * 256];   // 8KB
    __shared__ alignas(16) unsigned short A1[16 * 256];   // 8KB
    const int tid = threadIdx.x, lane = tid & 63, w = tid >> 6;
    const int lr = lane & 15, lq = lane >> 4;
    const int rg = blockIdx.x, b = blockIdx.y;
    const int a0 = rg * 16;

    // ---- reduce: wave w owns rows a0+w*4 .. a0+w*4+3; lane covers d=lane*4 ----
    {
        const int d0 = lane * 4;
        f32x4 r4[4];
        const f32x4 zero = {0.f, 0.f, 0.f, 0.f};
        #pragma unroll
        for (int j = 0; j < 4; ++j) r4[j] = zero;
        for (int c = 0; c < 32; ++c) {
            const float* base = y_part + (((size_t)b * 32 + c) * 64 + a0 + w * 4) * 256 + d0;
            #pragma unroll
            for (int j = 0; j < 4; ++j)
                r4[j] += *(const f32x4*)(base + (size_t)j * 256);
        }
        #pragma unroll
        for (int j = 0; j < 4; ++j) {
            const int a = w * 4 + j;
            s16x4 pk;
            #pragma unroll
            for (int e = 0; e < 4; ++e) pk[e] = (short)f2bf(r4[j][e]);
            *(s16x4*)((char*)A0 + a * 512 + ((d0 * 2) ^ ((a & 7) << 4))) = pk;
        }
    }
    __syncthreads();

    // ---- 3 GEMM stages, LDS ping-pong; C[16 rows][256 cols] per stage ----
    unsigned short* bufA = A0;
    unsigned short* bufB = A1;
    for (int s = 0; s < 3; ++s) {
        const unsigned short* W = Wb + (size_t)s * 65536;
        const float* bias = (s == 0) ? (b_qkv + 512) : (s == 1) ? b_fc1 : b_fc2;
        f32x4 acc[4];
        const f32x4 zero = {0.f, 0.f, 0.f, 0.f};
        #pragma unroll
        for (int cf = 0; cf < 4; ++cf) acc[cf] = zero;
        #pragma unroll
        for (int ks = 0; ks < 8; ++ks) {
            const int kb = ks * 64 + lq * 16;
            const int row = lr;
            s16x8 af = *(const s16x8*)((const char*)bufA + row * 512 + (kb ^ ((row & 7) << 4)));
            s16x8 bf[4];
            #pragma unroll
            for (int cf = 0; cf < 4; ++cf) {
                const int col = w * 64 + cf * 16 + lr;
                bf[cf] = *(const s16x8*)((const char*)W + (size_t)col * 512 + kb);
            }
            #pragma unroll
            for (int cf = 0; cf < 4; ++cf)
                acc[cf] = __builtin_amdgcn_mfma_f32_16x16x32_bf16(af, bf[cf], acc[cf], 0, 0, 0);
        }
        if (s < 2) {
            #pragma unroll
            for (int cf = 0; cf < 4; ++cf) {
                const int col = w * 64 + cf * 16 + lr;
                const float bv = bias[col];
                #pragma unroll
                for (int r = 0; r < 4; ++r) {
                    const int a = lq * 4 + r;
                    *(unsigned short*)((char*)bufB + a * 512 + ((col * 2) ^ ((a & 7) << 4)))
                        = f2bf(acc[cf][r] + bv);
                }
            }
            __syncthreads();
            unsigned short* t = bufA; bufA = bufB; bufB = t;
        } else {
            #pragma unroll
            for (int cf = 0; cf < 4; ++cf) {
                const int col = w * 64 + cf * 16 + lr;
                const float bv = bias[col];
                #pragma unroll
                for (int r = 0; r < 4; ++r) {
                    const int a = a0 + lq * 4 + r;
                    uu[((size_t)b * 64 + a) * 256 + col] = acc[cf][r] + bv;
                }
            }
        }
    }
}

// ---------------------------------------------------------------------------
// Stage-2 fused (R9 proven): P2 copy -> LDS, PV MFMA, residual + RMSNorm.
// ---------------------------------------------------------------------------
__global__ __launch_bounds__(256) void stage2_final(const unsigned short* __restrict__ P2,
                                                    const float* __restrict__ uu,
                                                    const float* __restrict__ x,
                                                    const float* __restrict__ nscale,
                                                    float* __restrict__ out)
{
    __shared__ alignas(16) unsigned short uT[256 * 64];  // [d][a] pitch 128B, swz
    __shared__ alignas(16) unsigned short P[64 * 64];    // [n][a] pitch 128B, swz
    __shared__ float ssq[4][64];
    const int tid = threadIdx.x, lane = tid & 63, w = tid >> 6;
    const int lr = lane & 15, lq = lane >> 4;
    const int b = blockIdx.x >> 7;
    const long n0 = (long)blockIdx.x * 64;

    {
        const int pr = tid >> 3;      // a-pair 0..31
        const int sub = tid & 7;
        const float* u0 = uu + ((size_t)b * 64 + 2 * pr) * 256;
        #pragma unroll
        for (int pass = 0; pass < 8; ++pass) {
            const int d0 = pass * 32 + sub * 4;
            f32x4 ua = *(const f32x4*)(u0 + d0);
            f32x4 ub = *(const f32x4*)(u0 + 256 + d0);
            #pragma unroll
            for (int jj = 0; jj < 4; ++jj) {
                const int d = d0 + jj;
                const unsigned int pk = (unsigned int)f2bf(ua[jj]) | ((unsigned int)f2bf(ub[jj]) << 16);
                *(unsigned int*)((char*)uT + d * 128 + ((pr * 4) ^ ((d & 7) << 4))) = pk;
            }
        }
    }
    {
        const int row = tid & 63, seg = tid >> 6;   // 4 segs x 32B
        const char* src = (const char*)P2 + (n0 + row) * 128 + seg * 32;
        s16x8 v0 = *(const s16x8*)src;
        s16x8 v1 = *(const s16x8*)(src + 16);
        *(s16x8*)((char*)P + row * 128 + seg * 32) = v0;
        *(s16x8*)((char*)P + row * 128 + seg * 32 + 16) = v1;
    }
    __syncthreads();

    f32x4 acc[4][4];
    const f32x4 zero = {0.f, 0.f, 0.f, 0.f};
    #pragma unroll
    for (int rf = 0; rf < 4; ++rf)
        #pragma unroll
        for (int cf = 0; cf < 4; ++cf)
            acc[rf][cf] = zero;
    #pragma unroll
    for (int ks = 0; ks < 2; ++ks) {
        const int kb = ks * 64 + lq * 16;
        s16x8 af[4], bfv[4];
        #pragma unroll
        for (int rf = 0; rf < 4; ++rf) {
            const int dR = w * 64 + rf * 16 + lr;
            af[rf] = *(const s16x8*)((const char*)uT + dR * 128 + (kb ^ ((dR & 7) << 4)));
        }
        #pragma unroll
        for (int cf = 0; cf < 4; ++cf) {
            const int nR = cf * 16 + lr;
            bfv[cf] = *(const s16x8*)((const char*)P + nR * 128 + (kb ^ ((nR & 7) << 4)));
        }
        #pragma unroll
        for (int rf = 0; rf < 4; ++rf)
            #pragma unroll
            for (int cf = 0; cf < 4; ++cf)
                acc[rf][cf] = __builtin_amdgcn_mfma_f32_16x16x32_bf16(
                    af[rf], bfv[cf], acc[rf][cf], 0, 0, 0);
    }

    float part[4] = {0.f, 0.f, 0.f, 0.f};
    #pragma unroll
    for (int cf = 0; cf < 4; ++cf) {
        const long n = n0 + cf * 16 + lr;
        #pragma unroll
        for (int rf = 0; rf < 4; ++rf) {
            const int d0 = w * 64 + rf * 16 + lq * 4;
            const f32x4 xr = *(const f32x4*)&x[n * 256 + d0];
            acc[rf][cf] += xr;
            part[cf] += acc[rf][cf][0] * acc[rf][cf][0] + acc[rf][cf][1] * acc[rf][cf][1]
                      + acc[rf][cf][2] * acc[rf][cf][2] + acc[rf][cf][3] * acc[rf][cf][3];
        }
    }
    #pragma unroll
    for (int cf = 0; cf < 4; ++cf) {
        float s = part[cf];
        s += __shfl_xor(s, 16);
        s += __shfl_xor(s, 32);
        if (lq == 0) ssq[w][cf * 16 + lr] = s;
    }
    __syncthreads();

    #pragma unroll
    for (int cf = 0; cf < 4; ++cf) {
        const int tokl = cf * 16 + lr;
        const float tot = ssq[0][tokl] + ssq[1][tokl] + ssq[2][tokl] + ssq[3][tokl];
        const float inv = 1.f / (sqrtf(tot) * 0.0625f + 1e-8f);
        const long n = n0 + tokl;
        #pragma unroll
        for (int rf = 0; rf < 4; ++rf) {
            const int d0 = w * 64 + rf * 16 + lq * 4;
            const f32x4 sc4 = *(const f32x4*)&nscale[d0];
            f32x4 o = sc4 * acc[rf][cf] * inv;
            *(f32x4*)&out[n * 256 + d0] = o;
        }
    }
}

// ---------------------------------------------------------------------------
extern "C" void kernel_launch(void* const* d_in, const int* in_sizes, int n_in,
                              void* d_out, int out_size, void* d_ws, size_t ws_size,
                              hipStream_t stream)
{
    const float* agent   = (const float*)d_in[0];
    const float* x       = (const float*)d_in[1];
    const float* W_qkv   = (const float*)d_in[2];
    const float* b_qkv   = (const float*)d_in[3];
    const float* W_agent = (const float*)d_in[4];
    const float* b_agent = (const float*)d_in[5];
    const float* W_fc1   = (const float*)d_in[6];
    const float* b_fc1   = (const float*)d_in[7];
    const float* W_fc2   = (const float*)d_in[8];
    const float* b_fc2   = (const float*)d_in[9];
    const float* nscale  = (const float*)d_in[10];
    float* out = (float*)d_out;

    char* wsp = (char*)d_ws;
    size_t off = 0;
    auto alloc = [&](size_t n) { void* p = wsp + off; off += (n + 255) & ~(size_t)255; return p; };

    unsigned short* MS = (unsigned short*)alloc(128UL * 256 * 2);
    float*  cbias  = (float*)alloc(128UL * 4);
    unsigned short* Wb = (unsigned short*)alloc(3UL * 256 * 256 * 2);
    float*  S1T    = (float*)alloc(65536UL * 64 * 4);              // [n][a] f32
    unsigned short* P2 = (unsigned short*)alloc(65536UL * 64 * 2); // [n][a] bf16 swz
    float*  mpart  = (float*)alloc(1024UL * 64 * 4);
    float*  lpart  = (float*)alloc(1024UL * 64 * 4);
    float*  y_part = (float*)alloc(8UL * 32 * 64 * 256 * 4);
    float*  uu     = (float*)alloc(512UL * 256 * 4);

    // 1. MS + cbias (agent proj fused) + bf16 weight conversion
    build_M2<<<320, 256, 0, stream>>>(W_qkv, b_qkv, agent, W_agent, b_agent,
                                      W_fc1, W_fc2, MS, cbias, Wb);
    // 2. streaming scores: S1T f32 + stage-1 partials; P2 = finalized stage-2 probs
    xproj2<<<1024, 256, 0, stream>>>(x, MS, cbias, S1T, P2, mpart, lpart);
    // 3. y = attn1 @ x via MFMA (stat combine fused; 2 blocks/CU)
    pv_mfma2<<<dim3(32, 2, 8), 256, 0, stream>>>(S1T, x, mpart, lpart, y_part);
    // 4. reduce + full fc chain (row-parallel, 32 blocks)
    chain_fused<<<dim3(4, 8), 256, 0, stream>>>(y_part, Wb, b_qkv, b_fc1, b_fc2, uu);
    // 5. P2 copy + PV MFMA + residual + rmsnorm
    stage2_final<<<1024, 256, 0, stream>>>(P2, uu, x, nscale, out);
}